// Round 11
// baseline (3124.703 us; speedup 1.0000x reference)
//
#include <hip/hip_runtime.h>

#define Tn 256
#define Bn 64
#define Xn 512
#define Hn 2048
#define Gn 8192  // 4*Hn
#define NWG 256

typedef short bf16x8 __attribute__((ext_vector_type(8)));
typedef float f32x4 __attribute__((ext_vector_type(4)));
typedef unsigned uint32x4 __attribute__((ext_vector_type(4)));

#define AL(p)    __hip_atomic_load((p), __ATOMIC_RELAXED, __HIP_MEMORY_SCOPE_AGENT)
#define AS(p, v) __hip_atomic_store((p), (v), __ATOMIC_RELAXED, __HIP_MEMORY_SCOPE_AGENT)
#define AADD(p, v) __hip_atomic_fetch_add((p), (v), __ATOMIC_RELAXED, __HIP_MEMORY_SCOPE_AGENT)

static __device__ __forceinline__ unsigned short f2bf(float f) {
    unsigned int u = __builtin_bit_cast(unsigned int, f);
    u += 0x7fffu + ((u >> 16) & 1u);
    return (unsigned short)(u >> 16);
}
static __device__ __forceinline__ float bf2f(unsigned short s) {
    unsigned int u = ((unsigned int)s) << 16;
    return __builtin_bit_cast(float, u);
}
static __device__ __forceinline__ void cvt4(const float* __restrict__ s,
                                            unsigned short* __restrict__ d, int i) {
    float4 v = ((const float4*)s)[i];
    ushort4 o;
    o.x = f2bf(v.x); o.y = f2bf(v.y); o.z = f2bf(v.z); o.w = f2bf(v.w);
    ((ushort4*)d)[i] = o;
}
static __device__ __forceinline__ float sigm(float x) {
    return 1.f / (1.f + __expf(-x));
}
static __device__ __forceinline__ float ftanh(float x) {
    float e = __expf(2.f * x);
    return (e - 1.f) / (e + 1.f);
}

// h buffer offset (bytes). RING: 129 buffers, index permuted by *67 mod 129
// (coprime) so successive steps aren't address-adjacent. Reuse distance 129
// steps ≈ 1.4 GB of intervening L2 traffic through 4 MB -> stale lines evicted.
template <int RING>
static __device__ __forceinline__ size_t hoff(int t) {
    if constexpr (RING) return (size_t)((t * 67) % 129) * 262144;
    else                return (size_t)(t & 1) * 262144;
}
template <int RING>
static __device__ __forceinline__ bf16x8 ldh(const unsigned short* p) {
    if constexpr (RING) {
        return *(const bf16x8*)p;
    } else {
        unsigned* q = (unsigned*)p;
        uint32x4 v;
        v[0] = AL(q + 0); v[1] = AL(q + 1); v[2] = AL(q + 2); v[3] = AL(q + 3);
        return __builtin_bit_cast(bf16x8, v);
    }
}
template <int RING>
static __device__ __forceinline__ float ldh1(const unsigned short* hb, int idx) {
    if constexpr (RING) {
        return bf2f(hb[idx]);
    } else {
        unsigned d = AL((unsigned*)(hb + (idx & ~1)));
        return bf2f((idx & 1) ? (unsigned short)(d >> 16) : (unsigned short)(d & 0xffffu));
    }
}

// ---------------- row-quarter gate ----------------
// Quarter q has 32 counters (64B apart) at flags + (q*32 + i)*16, i=0..31;
// counter i counts publishes of WGs i*8..i*8+7 for that quarter.
// Quarter ready for h(t) <=> all 32 counters >= 8*t. Lanes 0-31 poll.
static __device__ __forceinline__ void quarter_wait(const unsigned* qf, unsigned target, int l) {
    if (!target) return;
    const unsigned* p = qf + (l & 31) * 16;
    for (;;) {
        unsigned a = (l < 32) ? AL(p) : target;
        if (__all(a >= target)) break;
        __builtin_amdgcn_s_sleep(1);
    }
}

// ---------------- prologue ----------------
__global__ void prologue4(const float* __restrict__ x, const float* __restrict__ h0,
                          const float* __restrict__ b_ih, const float* __restrict__ b_hh,
                          const float* __restrict__ w_ih,
                          unsigned short* __restrict__ Xb, unsigned short* __restrict__ XFrag,
                          unsigned short* __restrict__ hb0, float* __restrict__ bias,
                          unsigned* __restrict__ flags)
{
    int i = blockIdx.x * blockDim.x + threadIdx.x;
    const int n_x  = Tn * Bn * Xn / 4;  // 2097152
    const int n_xf = Gn * Xn / 4;       // 1048576
    const int n_h  = Bn * Hn / 4;       // 32768
    const int n_b  = Gn / 4;            // 2048
    if (i < n_x) { cvt4(x, Xb, i); return; }
    i -= n_x;
    if (i < n_xf) {
        // Wih -> per-WG B-fragment layout (32 KB per WG)
        int wg = i >> 12, r = i & 4095;
        int c = r >> 7, k = (r & 127) * 4;
        int g = c >> 3, u = c & 7;
        float4 v = *(const float4*)(w_ih + (size_t)(g * Hn + wg * 8 + u) * Xn + k);
        ushort4 o;
        o.x = f2bf(v.x); o.y = f2bf(v.y); o.z = f2bf(v.z); o.w = f2bf(v.w);
        int ct = c >> 4, kk = k >> 5, l = ((k >> 3) & 3) * 16 + (c & 15);
        *(ushort4*)((char*)XFrag + (size_t)wg * 32768 + (size_t)((ct * 16 + kk) * 64 + l) * 16 + (k & 7) * 2) = o;
        return;
    }
    i -= n_xf;
    if (i < n_h) {
        // h0 -> blocked bf16 layout: elem(row,unit) at ((unit>>3)*64+row)*8+(unit&7)
        int flat = i * 4;
        int row = flat >> 11, unit0 = flat & 2047;
        float4 v = ((const float4*)h0)[i];
        ushort4 o;
        o.x = f2bf(v.x); o.y = f2bf(v.y); o.z = f2bf(v.z); o.w = f2bf(v.w);
        int dst = (((unit0 >> 3) << 6) + row) * 8 + (unit0 & 7);
        *(ushort4*)(hb0 + dst) = o;
        return;
    }
    i -= n_h;
    if (i < n_b) {
        float4 a = ((const float4*)b_ih)[i];
        float4 b = ((const float4*)b_hh)[i];
        ((float4*)bias)[i] = make_float4(a.x + b.x, a.y + b.y, a.z + b.z, a.w + b.w);
        return;
    }
    i -= n_b;
    if (i < 2048) flags[i] = 0u;   // 128 counters x 16 words
}

// ---------------- persistent LSTM: 4 waves x 16 rows x full K ----------------
// Wave w owns batch rows w*16..+15 for this WG's 8 units: full K GEMM (no RED,
// no intra-step barrier for wg>=64), local cell, per-row-quarter publish.
// Row-quarter w of h is produced and consumed ONLY by w-waves -> gate covers WAR.
// LDS: [0,131072) Whh B-frags; [131072,+32) RED2 (softmax partials).
template <int RING>
__global__ __launch_bounds__(256, 1) void lstm_persist8(
    const unsigned short* __restrict__ Xb, const unsigned short* __restrict__ XFrag,
    const float* __restrict__ bias, const float* __restrict__ c0,
    char* __restrict__ hbase, const float* __restrict__ w_hh,
    float* __restrict__ ys, float* __restrict__ hT, float* __restrict__ cT,
    unsigned* __restrict__ flags)
{
    extern __shared__ char smem[];
    const unsigned short* LW = (const unsigned short*)smem;
    float* RED2 = (float*)(smem + 131072);

    const int wg  = blockIdx.x;
    const int tid = threadIdx.x;
    const int U0  = wg * 8;

    // stage Whh slice -> LDS B-fragments (4 waves help)
    for (int i = tid; i < 32 * 512; i += 256) {
        int c = i >> 9, k = (i & 511) * 4;
        int g = c >> 3, u = c & 7;
        float4 v = *(const float4*)(w_hh + (size_t)(g * Hn + U0 + u) * Hn + k);
        ushort4 o;
        o.x = f2bf(v.x); o.y = f2bf(v.y); o.z = f2bf(v.z); o.w = f2bf(v.w);
        int ct = c >> 4, kk = k >> 5, l = ((k >> 3) & 3) * 16 + (c & 15);
        *(ushort4*)(smem + ((size_t)((ct * 64 + kk) * 64 + l) * 16 + (k & 7) * 2)) = o;
    }
    __syncthreads();

    const int w = tid >> 6, l = tid & 63;
    const int lm = l & 15, lh = l >> 4;
    const int R0 = w * 16;

    const int u  = lm & 7;
    const bool hi = (lm & 8) != 0;
    const int r0g = R0 + 4 * lh + (hi ? 2 : 0);   // this lane's rows r0g, r0g+1

    const float bi  = bias[0 * Hn + U0 + u];
    const float bf_ = bias[1 * Hn + U0 + u];
    const float bg  = bias[2 * Hn + U0 + u];
    const float bo  = bias[3 * Hn + U0 + u];
    float cs0 = c0[(size_t)r0g * Hn + U0 + u];
    float cs1 = c0[(size_t)(r0g + 1) * Hn + U0 + u];

    const char* xfb = (const char*)XFrag + (size_t)wg * 32768;
    const unsigned* qf = flags + w * 32 * 16;                 // my row-quarter gate
    unsigned* pubp = flags + (w * 32 + (wg >> 3)) * 16;       // my publish counter

    for (int t = 0; t < Tn; ++t) {
        const unsigned short* hb = (const unsigned short*)(hbase + hoff<RING>(t));
        unsigned short* hn = (unsigned short*)(hbase + hoff<RING>(t + 1));

        f32x4 acc0 = {0,0,0,0}, acc1 = {0,0,0,0};

        // ---- x-part: 16 rows x K=512 (independent of h(t), before the gate) ----
        {
            const unsigned short* xa = Xb + (size_t)(t * 64 + R0 + lm) * Xn + lh * 8;
            bf16x8 xA[4];
            #pragma unroll
            for (int j = 0; j < 4; ++j) xA[j] = *(const bf16x8*)(xa + j * 32);
            #pragma unroll 4
            for (int kk = 0; kk < 16; ++kk) {
                bf16x8 a = xA[kk & 3];
                if (kk < 12) xA[kk & 3] = *(const bf16x8*)(xa + (kk + 4) * 32);
                bf16x8 b0 = *(const bf16x8*)(xfb + ((size_t)((0 * 16 + kk) * 64 + l) << 4));
                bf16x8 b1 = *(const bf16x8*)(xfb + ((size_t)((1 * 16 + kk) * 64 + l) << 4));
                acc0 = __builtin_amdgcn_mfma_f32_16x16x32_bf16(a, b0, acc0, 0, 0, 0);
                acc1 = __builtin_amdgcn_mfma_f32_16x16x32_bf16(a, b1, acc1, 0, 0, 0);
            }
        }

        // ---- gate: my row-quarter of h(t), from my 256 producers (32 counters) ----
        quarter_wait(qf, (unsigned)t * 8u, l);

        // ---- h-part: 16 rows x full K=2048, 64 chunks, depth-8 prefetch ----
        {
            const unsigned short* ha = hb + (size_t)(R0 + lm) * 8;   // unit-group g at +g*512
            bf16x8 aP[8];
            #pragma unroll
            for (int j = 0; j < 8; ++j)
                aP[j] = ldh<RING>(ha + (size_t)(j * 4 + lh) * 512);
            #pragma unroll 8
            for (int kk = 0; kk < 64; ++kk) {
                bf16x8 a = aP[kk & 7];
                if (kk < 56)
                    aP[kk & 7] = ldh<RING>(ha + (size_t)((kk + 8) * 4 + lh) * 512);
                bf16x8 b0 = *(const bf16x8*)(LW + ((size_t)((0 * 64 + kk) * 64 + l) << 3));
                bf16x8 b1 = *(const bf16x8*)(LW + ((size_t)((1 * 64 + kk) * 64 + l) << 3));
                acc0 = __builtin_amdgcn_mfma_f32_16x16x32_bf16(a, b0, acc0, 0, 0, 0);
                acc1 = __builtin_amdgcn_mfma_f32_16x16x32_bf16(a, b1, acc1, 0, 0, 0);
            }
        }

        // ---- cell (local, no cross-wave combine) ----
        {
            f32x4 s0, s1;
            #pragma unroll
            for (int r = 0; r < 4; ++r) { s0[r] = __shfl_xor(acc0[r], 8); s1[r] = __shfl_xor(acc1[r], 8); }
            #pragma unroll
            for (int j = 0; j < 2; ++j) {
                int r = (hi ? 2 : 0) + j;
                float gi = (hi ? s0[r] : acc0[r]) + bi;
                float gf = (hi ? acc0[r] : s0[r]) + bf_;
                float gg = (hi ? s1[r] : acc1[r]) + bg;
                float go = (hi ? acc1[r] : s1[r]) + bo;
                float iv = sigm(gi), fv = sigm(gf), gv = ftanh(gg), ov = sigm(go);
                float cc = j ? cs1 : cs0;
                float cn = fv * cc + iv * gv;
                float hv = ov * ftanh(cn);
                if (j) cs1 = cn; else cs0 = cn;
                int rowg = r0g + j;
                unsigned short mybf = f2bf(hv);
                unsigned other = (unsigned)__shfl_xor((int)(unsigned)mybf, 1);
                if (!(u & 1)) {
                    AS((unsigned*)(hn + (size_t)wg * 512 + rowg * 8 + u),
                       (unsigned)mybf | (other << 16));
                }
                if (t == Tn - 1) {
                    size_t off = (size_t)rowg * Hn + U0 + u;
                    hT[off] = hv;
                    cT[off] = cn;
                }
            }
        }
        asm volatile("s_waitcnt vmcnt(0)" ::: "memory");

        // ---- rotating softmax assignment: row srow of h(t) -> ys[t-1] ----
        const int srow = wg - (t & 3) * 64;
        const bool sm = (srow >= 0) && (srow < Bn) && (t > 0);

        if (RING || !sm) {
            if (l == 0) AADD(pubp, 1u);    // ring: publish immediately
        }

        float sv[8];
        if (sm) {
            // gate the row's quarter (values), then wave-local partial
            quarter_wait(flags + (srow >> 4) * 32 * 16, (unsigned)t * 8u, l);
            float pm = -1e30f;
            #pragma unroll
            for (int j = 0; j < 8; ++j) {
                int uu = w * 512 + j * 64 + l;
                sv[j] = ldh1<RING>(hb, (uu >> 3) * 512 + srow * 8 + (uu & 7));
                pm = fmaxf(pm, sv[j]);
            }
            #pragma unroll
            for (int off = 32; off; off >>= 1) pm = fmaxf(pm, __shfl_xor(pm, off));
            float ps = 0.f;
            #pragma unroll
            for (int j = 0; j < 8; ++j) ps += __expf(sv[j] - pm);
            #pragma unroll
            for (int off = 32; off; off >>= 1) ps += __shfl_xor(ps, off);
            if (l == 0) { RED2[w * 2] = pm; RED2[w * 2 + 1] = ps; }
        }
        if (sm) __syncthreads();           // WG-uniform (sm uniform per WG)
        if constexpr (!RING) {
            if (sm && l == 0) AADD(pubp, 1u);  // bypass: publish after WG-wide h(t) reads
        }
        if (sm) {
            float m0 = RED2[0], sA = RED2[1], m1 = RED2[2], sB = RED2[3];
            float m2 = RED2[4], sC = RED2[5], m3 = RED2[6], sD = RED2[7];
            float gm = fmaxf(fmaxf(m0, m1), fmaxf(m2, m3));
            float gs = sA * __expf(m0 - gm) + sB * __expf(m1 - gm) +
                       sC * __expf(m2 - gm) + sD * __expf(m3 - gm);
            float inv = 1.f / gs;
            float* yr = ys + ((size_t)(t - 1) * Bn + srow) * Hn + w * 512;
            #pragma unroll
            for (int j = 0; j < 8; ++j) yr[j * 64 + l] = __expf(sv[j] - gm) * inv;
            __syncthreads();               // RED2 WAR for next use
        }
    }

    // ---- final softmax on h(Tn): rotation at t=Tn gives rows = wg (wg<64) ----
    {
        const unsigned short* hfin = (const unsigned short*)(hbase + hoff<RING>(Tn));
        const int srow = wg;               // (Tn & 3) == 0
        const bool act = (srow < Bn);
        float sv[8];
        if (act) {
            quarter_wait(flags + (srow >> 4) * 32 * 16, (unsigned)Tn * 8u, l);
            float pm = -1e30f;
            #pragma unroll
            for (int j = 0; j < 8; ++j) {
                int uu = w * 512 + j * 64 + l;
                sv[j] = ldh1<RING>(hfin, (uu >> 3) * 512 + srow * 8 + (uu & 7));
                pm = fmaxf(pm, sv[j]);
            }
            #pragma unroll
            for (int off = 32; off; off >>= 1) pm = fmaxf(pm, __shfl_xor(pm, off));
            float ps = 0.f;
            #pragma unroll
            for (int j = 0; j < 8; ++j) ps += __expf(sv[j] - pm);
            #pragma unroll
            for (int off = 32; off; off >>= 1) ps += __shfl_xor(ps, off);
            if (l == 0) { RED2[w * 2] = pm; RED2[w * 2 + 1] = ps; }
        }
        __syncthreads();
        if (act) {
            float m0 = RED2[0], sA = RED2[1], m1 = RED2[2], sB = RED2[3];
            float m2 = RED2[4], sC = RED2[5], m3 = RED2[6], sD = RED2[7];
            float gm = fmaxf(fmaxf(m0, m1), fmaxf(m2, m3));
            float gs = sA * __expf(m0 - gm) + sB * __expf(m1 - gm) +
                       sC * __expf(m2 - gm) + sD * __expf(m3 - gm);
            float inv = 1.f / gs;
            float* yr = ys + ((size_t)(Tn - 1) * Bn + srow) * Hn + w * 512;
            #pragma unroll
            for (int j = 0; j < 8; ++j) yr[j * 64 + l] = __expf(sv[j] - gm) * inv;
        }
    }
}

// ---------------- host ----------------
extern "C" void kernel_launch(void* const* d_in, const int* in_sizes, int n_in,
                              void* d_out, int out_size, void* d_ws, size_t ws_size,
                              hipStream_t stream) {
    const float* input = (const float*)d_in[0];
    const float* h0    = (const float*)d_in[1];
    const float* c0    = (const float*)d_in[2];
    const float* w_ih  = (const float*)d_in[3];
    const float* w_hh  = (const float*)d_in[4];
    const float* b_ih  = (const float*)d_in[5];
    const float* b_hh  = (const float*)d_in[6];

    float* ys = (float*)d_out;                    // [256][64][2048]
    float* hT = ys + (size_t)Tn * Bn * Hn;        // [64][2048]
    float* cT = hT + (size_t)Bn * Hn;             // [64][2048]

    char* wsb = (char*)d_ws;
    unsigned short* Xb  = (unsigned short*)wsb;                  // 16,777,216
    unsigned short* XF  = (unsigned short*)(wsb + 16777216);     //  8,388,608
    float* bias         = (float*)(wsb + 25165824);              //     32,768
    unsigned* flags     = (unsigned*)(wsb + 25198592);           //      8,192 (128 ctr x 64B)
    char* hbase         = wsb + 25206784;                        // h buffers
    const size_t need_ring = 25206784 + (size_t)129 * 262144;    // 59,023,360
    // bypass need = 25,206,784 + 524,288 = 25,731,072

    const int prol_items = Tn * Bn * Xn / 4 + Gn * Xn / 4 + Bn * Hn / 4 + Gn / 4 + 2048;
    const int prol_blocks = (prol_items + 255) / 256;
    prologue4<<<dim3(prol_blocks), dim3(256), 0, stream>>>(
        input, h0, b_ih, b_hh, w_ih, Xb, XF, (unsigned short*)hbase, bias, flags);

    if (ws_size >= need_ring) {
        (void)hipFuncSetAttribute((const void*)lstm_persist8<1>,
                                  hipFuncAttributeMaxDynamicSharedMemorySize, 131136);
        lstm_persist8<1><<<dim3(NWG), dim3(256), 131136, stream>>>(
            Xb, XF, bias, c0, hbase, w_hh, ys, hT, cT, flags);
    } else {
        (void)hipFuncSetAttribute((const void*)lstm_persist8<0>,
                                  hipFuncAttributeMaxDynamicSharedMemorySize, 131136);
        lstm_persist8<0><<<dim3(NWG), dim3(256), 131136, stream>>>(
            Xb, XF, bias, c0, hbase, w_hh, ys, hT, cT, flags);
    }
}

// Round 12
// 1895.830 us; speedup vs baseline: 1.6482x; 1.6482x over previous
//
#include <hip/hip_runtime.h>

#define Tn 256
#define Bn 64
#define Xn 512
#define Hn 2048
#define Gn 8192  // 4*Hn
#define NWG 256

typedef short bf16x8 __attribute__((ext_vector_type(8)));
typedef float f32x4 __attribute__((ext_vector_type(4)));
typedef unsigned uint32x4 __attribute__((ext_vector_type(4)));

#define AL(p)    __hip_atomic_load((p), __ATOMIC_RELAXED, __HIP_MEMORY_SCOPE_AGENT)
#define AS(p, v) __hip_atomic_store((p), (v), __ATOMIC_RELAXED, __HIP_MEMORY_SCOPE_AGENT)
#define AADD(p, v) __hip_atomic_fetch_add((p), (v), __ATOMIC_RELAXED, __HIP_MEMORY_SCOPE_AGENT)

static __device__ __forceinline__ unsigned short f2bf(float f) {
    unsigned int u = __builtin_bit_cast(unsigned int, f);
    u += 0x7fffu + ((u >> 16) & 1u);
    return (unsigned short)(u >> 16);
}
static __device__ __forceinline__ float bf2f(unsigned short s) {
    unsigned int u = ((unsigned int)s) << 16;
    return __builtin_bit_cast(float, u);
}
static __device__ __forceinline__ void cvt4(const float* __restrict__ s,
                                            unsigned short* __restrict__ d, int i) {
    float4 v = ((const float4*)s)[i];
    ushort4 o;
    o.x = f2bf(v.x); o.y = f2bf(v.y); o.z = f2bf(v.z); o.w = f2bf(v.w);
    ((ushort4*)d)[i] = o;
}
static __device__ __forceinline__ float sigm(float x) {
    return 1.f / (1.f + __expf(-x));
}
static __device__ __forceinline__ float ftanh(float x) {
    float e = __expf(2.f * x);
    return (e - 1.f) / (e + 1.f);
}

// h buffer offset within the ring (bytes). RING: 257 buffers, index permuted.
template <int RING>
static __device__ __forceinline__ size_t hoff(int t) {
    if constexpr (RING) return (size_t)((t * 97) % 257) * 262144;
    else                return (size_t)(t & 1) * 262144;
}
template <int RING>
static __device__ __forceinline__ bf16x8 ldh(const unsigned short* p) {
    if constexpr (RING) {
        return *(const bf16x8*)p;
    } else {
        unsigned* q = (unsigned*)p;
        uint32x4 v;
        v[0] = AL(q + 0); v[1] = AL(q + 1); v[2] = AL(q + 2); v[3] = AL(q + 3);
        return __builtin_bit_cast(bf16x8, v);
    }
}
template <int RING>
static __device__ __forceinline__ float ldh1(const unsigned short* hb, int idx) {
    if constexpr (RING) {
        return bf2f(hb[idx]);
    } else {
        unsigned d = AL((unsigned*)(hb + (idx & ~1)));
        return bf2f((idx & 1) ? (unsigned short)(d >> 16) : (unsigned short)(d & 0xffffu));
    }
}

// ---------------- 8-shard wait (shards of 8 WGs, 64B apart) ----------------
// Counter i (at sh[i*16]) counts publishes of WGs i*8..i*8+7 for one row-half.
// Slice ready for h(t) <=> counters base..base+7 all >= 8*t. Lanes 0-7 poll.
static __device__ __forceinline__ void oct_wait(const unsigned* sh, int base,
                                                unsigned target, int l) {
    if (!target) return;
    const unsigned* p = sh + (base + (l & 7)) * 16;
    for (;;) {
        unsigned a = (l < 8) ? AL(p) : target;
        if (__all(a >= target)) break;
        __builtin_amdgcn_s_sleep(1);
    }
}
// Full row-half wait: all 32 counters of one row-half >= target. Lanes 0-31 poll.
static __device__ __forceinline__ void half_wait(const unsigned* hf, unsigned target, int l) {
    if (!target) return;
    const unsigned* p = hf + (l & 31) * 16;
    for (;;) {
        unsigned a = (l < 32) ? AL(p) : target;
        if (__all(a >= target)) break;
        __builtin_amdgcn_s_sleep(1);
    }
}

// ---------------- solo full-row softmax (one wave, 32 values/lane) ----------------
// blocked h layout: unit u of row at (u>>3)*512 + row*8 + (u&7)
template <int RING>
static __device__ __forceinline__ void solo_softmax(const unsigned short* hb, int row,
                                                    float* __restrict__ yr, int l) {
    float v[32];
    float m = -1e30f;
    #pragma unroll
    for (int i = 0; i < 32; ++i) {
        int idx = (i * 8 + (l >> 3)) * 512 + row * 8 + (l & 7);   // unit i*64+l
        v[i] = ldh1<RING>(hb, idx);
        m = fmaxf(m, v[i]);
    }
    #pragma unroll
    for (int off = 32; off; off >>= 1) m = fmaxf(m, __shfl_xor(m, off));
    float s = 0.f;
    #pragma unroll
    for (int i = 0; i < 32; ++i) { v[i] = __expf(v[i] - m); s += v[i]; }
    #pragma unroll
    for (int off = 32; off; off >>= 1) s += __shfl_xor(s, off);
    float inv = 1.f / s;
    #pragma unroll
    for (int i = 0; i < 32; ++i) yr[i * 64 + l] = v[i] * inv;
}

// ---------------- prologue ----------------
__global__ void prologue3(const float* __restrict__ x, const float* __restrict__ h0,
                          const float* __restrict__ b_ih, const float* __restrict__ b_hh,
                          const float* __restrict__ w_ih,
                          unsigned short* __restrict__ Xb, unsigned short* __restrict__ XFrag,
                          unsigned short* __restrict__ hb0, float* __restrict__ bias,
                          unsigned* __restrict__ flags)
{
    int i = blockIdx.x * blockDim.x + threadIdx.x;
    const int n_x  = Tn * Bn * Xn / 4;  // 2097152
    const int n_xf = Gn * Xn / 4;       // 1048576
    const int n_h  = Bn * Hn / 4;       // 32768
    const int n_b  = Gn / 4;            // 2048
    if (i < n_x) { cvt4(x, Xb, i); return; }
    i -= n_x;
    if (i < n_xf) {
        // Wih -> per-WG B-fragment layout (32 KB per WG)
        int wg = i >> 12, r = i & 4095;
        int c = r >> 7, k = (r & 127) * 4;
        int g = c >> 3, u = c & 7;
        float4 v = *(const float4*)(w_ih + (size_t)(g * Hn + wg * 8 + u) * Xn + k);
        ushort4 o;
        o.x = f2bf(v.x); o.y = f2bf(v.y); o.z = f2bf(v.z); o.w = f2bf(v.w);
        int ct = c >> 4, kk = k >> 5, l = ((k >> 3) & 3) * 16 + (c & 15);
        *(ushort4*)((char*)XFrag + (size_t)wg * 32768 + (size_t)((ct * 16 + kk) * 64 + l) * 16 + (k & 7) * 2) = o;
        return;
    }
    i -= n_xf;
    if (i < n_h) {
        // h0 -> blocked bf16 layout: elem(row,unit) at ((unit>>3)*64+row)*8+(unit&7)
        int flat = i * 4;
        int row = flat >> 11, unit0 = flat & 2047;
        float4 v = ((const float4*)h0)[i];
        ushort4 o;
        o.x = f2bf(v.x); o.y = f2bf(v.y); o.z = f2bf(v.z); o.w = f2bf(v.w);
        int dst = (((unit0 >> 3) << 6) + row) * 8 + (unit0 & 7);
        *(ushort4*)(hb0 + dst) = o;
        return;
    }
    i -= n_h;
    if (i < n_b) {
        float4 a = ((const float4*)b_ih)[i];
        float4 b = ((const float4*)b_hh)[i];
        ((float4*)bias)[i] = make_float4(a.x + b.x, a.y + b.y, a.z + b.z, a.w + b.w);
        return;
    }
    i -= n_b;
    if (i < 1024) flags[i] = 0u;   // rowhalf A shards [0,512), rowhalf B shards [512,1024)
}

#define MFMA4(a0v, a1v) \
    acc00 = __builtin_amdgcn_mfma_f32_16x16x32_bf16((a0v), b0, acc00, 0, 0, 0); \
    acc10 = __builtin_amdgcn_mfma_f32_16x16x32_bf16((a1v), b0, acc10, 0, 0, 0); \
    acc01 = __builtin_amdgcn_mfma_f32_16x16x32_bf16((a0v), b1, acc01, 0, 0, 0); \
    acc11 = __builtin_amdgcn_mfma_f32_16x16x32_bf16((a1v), b1, acc11, 0, 0, 0);

// ---------------- persistent LSTM, 8 waves = 4 K-quarters x 2 row-halves ----------------
// Same as round-10 base. Diff: softmax is a SOLO wave-7 job, post-barrier, rotating
// across WG-quarters (q = t&3, WGs q*64..q*64+63, row = wg - q*64) — off the
// publish-critical path. No RED2, no phase split.
// LDS: [0,131072) Whh B-frags; [131072,155648) RED.
template <int RING>
__global__ __launch_bounds__(512, 1) void lstm_persist9(
    const unsigned short* __restrict__ Xb, const unsigned short* __restrict__ XFrag,
    const float* __restrict__ bias, const float* __restrict__ c0,
    char* __restrict__ hbase, const float* __restrict__ w_hh,
    float* __restrict__ ys, float* __restrict__ hT, float* __restrict__ cT,
    unsigned* __restrict__ flags)
{
    extern __shared__ char smem[];
    const unsigned short* LW = (const unsigned short*)smem;
    float* RED = (float*)(smem + 131072);

    const int wg  = blockIdx.x;
    const int tid = threadIdx.x;
    const int U0  = wg * 8;

    // stage Whh slice -> LDS B-fragments (all 8 waves help)
    for (int i = tid; i < 32 * 512; i += 512) {
        int c = i >> 9, k = (i & 511) * 4;
        int g = c >> 3, u = c & 7;
        float4 v = *(const float4*)(w_hh + (size_t)(g * Hn + U0 + u) * Hn + k);
        ushort4 o;
        o.x = f2bf(v.x); o.y = f2bf(v.y); o.z = f2bf(v.z); o.w = f2bf(v.w);
        int ct = c >> 4, kk = k >> 5, l = ((k >> 3) & 3) * 16 + (c & 15);
        *(ushort4*)(smem + ((size_t)((ct * 64 + kk) * 64 + l) * 16 + (k & 7) * 2)) = o;
    }
    __syncthreads();

    const int w = tid >> 6, l = tid & 63;
    const int lm = l & 15, lh = l >> 4;
    const int kh = w >> 1, rblk = w & 1, rb = rblk * 32;
    const int kk0 = kh * 16;   // h-part: 16 chunks of K=32 per quarter
    const int kx0 = kh * 4;    // x-part: 4 chunks of K=32 per quarter

    const int u  = lm & 7;
    const bool hi = (lm & 8) != 0;

    float bi = 0.f, bf_ = 0.f, bg = 0.f, bo = 0.f;
    float cs[2][2] = {{0.f, 0.f}, {0.f, 0.f}};
    if (kh == 0) {
        bi  = bias[0 * Hn + U0 + u];
        bf_ = bias[1 * Hn + U0 + u];
        bg  = bias[2 * Hn + U0 + u];
        bo  = bias[3 * Hn + U0 + u];
        #pragma unroll
        for (int s = 0; s < 2; ++s)
            #pragma unroll
            for (int j = 0; j < 2; ++j)
                cs[s][j] = c0[(size_t)(rb + s * 16 + 4 * lh + (hi ? 2 : 0) + j) * Hn + U0 + u];
    }

    const char* xfb = (const char*)XFrag + (size_t)wg * 32768;
    const unsigned* gate_f = flags + rblk * 512;   // this wave's row-half shards

    for (int t = 0; t < Tn; ++t) {
        const unsigned short* hb = (const unsigned short*)(hbase + hoff<RING>(t));
        unsigned short* hn = (unsigned short*)(hbase + hoff<RING>(t + 1));

        f32x4 acc00 = {0,0,0,0}, acc01 = {0,0,0,0}, acc10 = {0,0,0,0}, acc11 = {0,0,0,0};

        // ---- x-part (this wave's K-quarter of 512): before the shard wait ----
        {
            const unsigned short* xa0 = Xb + (size_t)(t * 64 + rb + lm) * Xn + lh * 8;
            const unsigned short* xa1 = xa0 + 16 * Xn;
            bf16x8 xA0[4], xA1[4];
            #pragma unroll
            for (int j = 0; j < 4; ++j) {
                xA0[j] = *(const bf16x8*)(xa0 + (kx0 + j) * 32);
                xA1[j] = *(const bf16x8*)(xa1 + (kx0 + j) * 32);
            }
            #pragma unroll
            for (int kkl = 0; kkl < 4; ++kkl) {
                bf16x8 b0 = *(const bf16x8*)(xfb + ((size_t)((0 * 16 + kx0 + kkl) * 64 + l) << 4));
                bf16x8 b1 = *(const bf16x8*)(xfb + ((size_t)((1 * 16 + kx0 + kkl) * 64 + l) << 4));
                MFMA4(xA0[kkl], xA1[kkl]);
            }
        }

        // ---- per-wave gate: the 8 shards covering this wave's 64 producers ----
        oct_wait(gate_f, kh * 8, (unsigned)t * 8u, l);

        // ---- h-part (this wave's K-quarter of 2048), depth-4x2 prefetch ----
        {
            const unsigned short* ha0 = hb + (size_t)(rb + lm) * 8;   // chunk g at +g*512
            const unsigned short* ha1 = ha0 + 128;                    // +16 rows
            bf16x8 aP0[4], aP1[4];
            #pragma unroll
            for (int j = 0; j < 4; ++j) {
                int g = (kk0 + j) * 4 + lh;
                aP0[j] = ldh<RING>(ha0 + (size_t)g * 512);
                aP1[j] = ldh<RING>(ha1 + (size_t)g * 512);
            }
            #pragma unroll 4
            for (int kkl = 0; kkl < 16; ++kkl) {
                bf16x8 a0v = aP0[kkl & 3], a1v = aP1[kkl & 3];
                if (kkl < 12) {
                    int g = (kk0 + kkl + 4) * 4 + lh;
                    aP0[kkl & 3] = ldh<RING>(ha0 + (size_t)g * 512);
                    aP1[kkl & 3] = ldh<RING>(ha1 + (size_t)g * 512);
                }
                bf16x8 b0 = *(const bf16x8*)(LW + ((size_t)((0 * 64 + kk0 + kkl) * 64 + l) << 3));
                bf16x8 b1 = *(const bf16x8*)(LW + ((size_t)((1 * 64 + kk0 + kkl) * 64 + l) << 3));
                MFMA4(a0v, a1v);
            }
        }

        if (kh != 0) {
            // dump partials: per-acc contiguous regions -> conflict-free ds_write_b128
            int slot = (kh - 1) * 2 + rblk;
            int base = (slot * 64 + l) * 4;
            *(f32x4*)(RED + 0 * 1536 + base) = acc00;
            *(f32x4*)(RED + 1 * 1536 + base) = acc01;
            *(f32x4*)(RED + 2 * 1536 + base) = acc10;
            *(f32x4*)(RED + 3 * 1536 + base) = acc11;
        }
        __syncthreads();

        if (kh == 0) {
            // combine 3 K-quarter partials, then the cell, then EARLY per-half publish
            #pragma unroll
            for (int p = 0; p < 3; ++p) {
                int base = ((p * 2 + rblk) * 64 + l) * 4;
                acc00 += *(const f32x4*)(RED + 0 * 1536 + base);
                acc01 += *(const f32x4*)(RED + 1 * 1536 + base);
                acc10 += *(const f32x4*)(RED + 2 * 1536 + base);
                acc11 += *(const f32x4*)(RED + 3 * 1536 + base);
            }
            f32x4 sA[2], sB[2];
            #pragma unroll
            for (int r = 0; r < 4; ++r) {
                sA[0][r] = __shfl_xor(acc00[r], 8); sB[0][r] = __shfl_xor(acc01[r], 8);
                sA[1][r] = __shfl_xor(acc10[r], 8); sB[1][r] = __shfl_xor(acc11[r], 8);
            }
            #pragma unroll
            for (int s = 0; s < 2; ++s) {
                f32x4 aA = s ? acc10 : acc00;
                f32x4 aB = s ? acc11 : acc01;
                #pragma unroll
                for (int j = 0; j < 2; ++j) {
                    int r = (hi ? 2 : 0) + j;
                    float gi = (hi ? sA[s][r] : aA[r]) + bi;
                    float gf = (hi ? aA[r] : sA[s][r]) + bf_;
                    float gg = (hi ? sB[s][r] : aB[r]) + bg;
                    float go = (hi ? aB[r] : sB[s][r]) + bo;
                    float iv = sigm(gi), fv = sigm(gf), gv = ftanh(gg), ov = sigm(go);
                    float cc = cs[s][j];
                    float cn = fv * cc + iv * gv;
                    float hv = ov * ftanh(cn);
                    cs[s][j] = cn;
                    int rowg = rb + s * 16 + 4 * lh + (hi ? 2 : 0) + j;
                    // pack lane-pair (u, u^1) -> one coherent dword store
                    unsigned short mybf = f2bf(hv);
                    unsigned other = (unsigned)__shfl_xor((int)(unsigned)mybf, 1);
                    if (!(u & 1)) {
                        AS((unsigned*)(hn + (size_t)wg * 512 + rowg * 8 + u),
                           (unsigned)mybf | (other << 16));
                    }
                    if (t == Tn - 1) {
                        size_t off = (size_t)rowg * Hn + U0 + u;
                        hT[off] = hv;
                        cT[off] = cn;
                    }
                }
            }
            // drain own h stores, publish this row-half's shard immediately
            asm volatile("s_waitcnt vmcnt(0)" ::: "memory");
            if (l == 0) AADD((unsigned*)(flags + rblk * 512 + (wg >> 3) * 16), 1u);
        }
        __syncthreads();   // RED WAR protection only

        // ---- solo softmax (wave 7, rotating quarter) — off the publish path ----
        if (w == 7 && t > 0) {
            int srow = wg - (t & 3) * 64;
            if (srow >= 0 && srow < Bn) {
                half_wait(flags + (srow >= 32 ? 512 : 0), (unsigned)t * 8u, l);
                solo_softmax<RING>(hb, srow, ys + ((size_t)(t - 1) * Bn + srow) * Hn, l);
            }
        }
    }

    // ---- final softmax on h(Tn): quarter 0 (Tn&3==0) -> WGs 0..63, row = wg ----
    if (w == 7 && wg < Bn) {
        const unsigned short* hfin = (const unsigned short*)(hbase + hoff<RING>(Tn));
        half_wait(flags + (wg >= 32 ? 512 : 0), (unsigned)Tn * 8u, l);
        solo_softmax<RING>(hfin, wg, ys + ((size_t)(Tn - 1) * Bn + wg) * Hn, l);
    }
}

// ---------------- host ----------------
extern "C" void kernel_launch(void* const* d_in, const int* in_sizes, int n_in,
                              void* d_out, int out_size, void* d_ws, size_t ws_size,
                              hipStream_t stream) {
    const float* input = (const float*)d_in[0];
    const float* h0    = (const float*)d_in[1];
    const float* c0    = (const float*)d_in[2];
    const float* w_ih  = (const float*)d_in[3];
    const float* w_hh  = (const float*)d_in[4];
    const float* b_ih  = (const float*)d_in[5];
    const float* b_hh  = (const float*)d_in[6];

    float* ys = (float*)d_out;                    // [256][64][2048]
    float* hT = ys + (size_t)Tn * Bn * Hn;        // [64][2048]
    float* cT = hT + (size_t)Bn * Hn;             // [64][2048]

    char* wsb = (char*)d_ws;
    unsigned short* Xb  = (unsigned short*)wsb;                  // 16,777,216
    unsigned short* XF  = (unsigned short*)(wsb + 16777216);     //  8,388,608
    float* bias         = (float*)(wsb + 25165824);              //     32,768
    unsigned* flags     = (unsigned*)(wsb + 25198592);           //      4,096 (A:512w, B:512w)
    char* hbase         = wsb + 25202688;                        // h buffers
    const size_t need_ring = 25202688 + (size_t)257 * 262144;    // 92,573,696
    // bypass need = 25,202,688 + 524,288 = 25,726,976

    const int prol_items = Tn * Bn * Xn / 4 + Gn * Xn / 4 + Bn * Hn / 4 + Gn / 4 + 1024;
    const int prol_blocks = (prol_items + 255) / 256;
    prologue3<<<dim3(prol_blocks), dim3(256), 0, stream>>>(
        input, h0, b_ih, b_hh, w_ih, Xb, XF, (unsigned short*)hbase, bias, flags);

    if (ws_size >= need_ring) {
        (void)hipFuncSetAttribute((const void*)lstm_persist9<1>,
                                  hipFuncAttributeMaxDynamicSharedMemorySize, 155648);
        lstm_persist9<1><<<dim3(NWG), dim3(512), 155648, stream>>>(
            Xb, XF, bias, c0, hbase, w_hh, ys, hT, cT, flags);
    } else {
        (void)hipFuncSetAttribute((const void*)lstm_persist9<0>,
                                  hipFuncAttributeMaxDynamicSharedMemorySize, 155648);
        lstm_persist9<0><<<dim3(NWG), dim3(512), 155648, stream>>>(
            Xb, XF, bias, c0, hbase, w_hh, ys, hT, cT, flags);
    }
}